// Round 1
// baseline (4654.366 us; speedup 1.0000x reference)
//
#include <hip/hip_runtime.h>
#include <math.h>

#define SEQ 1000
#define IND 76
// padded index into 25-per-group / 28-stride activation tile arrays
#define PIDX(i) ((((i)/25)*28) + ((i)%25))

__device__ __forceinline__ float sigf(float v) { return 1.0f / (1.0f + expf(-v)); }

// Roles (t = threadIdx.x, 512 threads):
//  t in [0,200)    : EARLY slots: stage2-early (rows 4g..4g+3 of [Wm;Wa], cols 100+25c, acts lm/lb)
//                    + dx-early (rows 2g,2g+1 of Wx, cols 100+25c, acts ls) + readout partial
//  t in [0,400)    : L2 row t (38 masked cols, acts kin2 branch window)
//  t in [200,219)  : xt prefetch (1 float4 each, issued B0, written B2)
//  t in [256,456)  : LATE slots s=t-256: stage2-late (cols 25c, acts dx) + dx-late (cols 25c, acts s2)
//  t in [456,506)  : L1 neuron n=t-456 (4 branch rows, full state in-thread), pipelined one step ahead
//  t < 100         : liquid neuron owner (m2/lm/lb/ls state in regs), reducers
__global__ __launch_bounds__(512) void dhsnn_fwd(
    const float* __restrict__ x,
    const float* __restrict__ W1, const float* __restrict__ b1,
    const float* __restrict__ tau_m1, const float* __restrict__ tau_n1,
    const float* __restrict__ W2, const float* __restrict__ b2,
    const float* __restrict__ tau_m2, const float* __restrict__ tau_n2,
    const float* __restrict__ Wxp, const float* __restrict__ bxp,
    const float* __restrict__ Wm, const float* __restrict__ bm,
    const float* __restrict__ Wa, const float* __restrict__ ba,
    const float* __restrict__ Wd, const float* __restrict__ bd,
    const float* __restrict__ tau_md,
    float* __restrict__ out)
{
    const int t   = (int)threadIdx.x;
    const int blk = (int)blockIdx.x;

    __shared__ __align__(16) float kin1P[128];     // [0..75] xt(j+1), [76..125] s1(j), pad 0
    __shared__ __align__(16) float kin2P[4][40];   // branch windows of [s1(50), s2(100)], pad 0
    __shared__ __align__(16) float s1stage[56];
    __shared__ __align__(16) float dsum[400];      // post-update d2 per L2 row
    __shared__ __align__(16) float dpart[8][100];  // dx partials: [c]=early(ls), [4+c]=late(s2)
    __shared__ __align__(16) float spart[8][200];  // stage2 partials: [c]=early, [4+c]=late
    __shared__ __align__(16) float dxP[112];       // padded 25/28 tiles
    __shared__ __align__(16) float s2P[112];
    __shared__ __align__(16) float lsP[112];
    __shared__ __align__(16) float lmP[112];
    __shared__ __align__(16) float lbP[112];
    __shared__ __align__(16) float tauA_s[100];
    __shared__ __align__(16) float rpart[200];
    __shared__ __align__(16) float r2[8];

    // ---- zero LDS ----
    for (int i = t; i < 128;  i += 512) kin1P[i] = 0.f;
    for (int i = t; i < 160;  i += 512) (&kin2P[0][0])[i] = 0.f;
    for (int i = t; i < 56;   i += 512) s1stage[i] = 0.f;
    for (int i = t; i < 400;  i += 512) dsum[i] = 0.f;
    for (int i = t; i < 800;  i += 512) (&dpart[0][0])[i] = 0.f;
    for (int i = t; i < 1600; i += 512) (&spart[0][0])[i] = 0.f;
    for (int i = t; i < 112;  i += 512) { dxP[i]=0.f; s2P[i]=0.f; lsP[i]=0.f; lmP[i]=0.f; lbP[i]=0.f; }
    for (int i = t; i < 100;  i += 512) tauA_s[i] = 0.f;
    for (int i = t; i < 200;  i += 512) rpart[i] = 0.f;
    for (int i = t; i < 8;    i += 512) r2[i] = 0.f;

    // ---- unioned register files ----
    // wreg map:
    //  t<200:        [0..99] wSe(4x25), [100..149] wXe(2x25), [150..187] w2(38)
    //  t in[200,400):[150..187] w2
    //  t in[256,456):[0..99] wSl, [100..149] wXl, (+[150..187] w2 if t<400)
    //  t in[456,506):[0..127] w1(4x32)
    float wreg[188];
    // sc map: t<400: 0=b2,1=beta2 ; t<100: 2=alpha2,3=bx,4=bm ; t in[100,200):4=ba ;
    //         t<200: 5=wd ; t<2: 6=ad,7=bd ; t in[456,506): 0..3=b1,4..7=beta1,8=alpha1
    float sc[10];
    // st map: t<400: 0=d2 ; t<100: 1=m2,2=lm,3=lb,4=ls,5=dx,6=tauM,7=s2spk ;
    //         t in[456,506): 0..3=d1,4=m1,5=s1spk
    float st[8];
    float mdr = 0.f, accr = 0.f;
    float4 xp0;
    #pragma unroll
    for (int i = 0; i < 10; ++i) sc[i] = 0.f;
    #pragma unroll
    for (int i = 0; i < 8; ++i)  st[i] = 0.f;

    if (t < 456) {
        const bool late = (t >= 256);
        const int  s    = late ? (t - 256) : t;
        if (s < 200) {
            const int g = s >> 2, c = s & 3;
            const int colbase = late ? (25 * c) : (100 + 25 * c);
            #pragma unroll
            for (int k = 0; k < 4; ++k) {
                const int row = 4 * g + k;
                const float* Wrow = (row < 100) ? (Wm + row * 200) : (Wa + (row - 100) * 200);
                #pragma unroll
                for (int u = 0; u < 25; ++u) wreg[k * 25 + u] = Wrow[colbase + u];
            }
            #pragma unroll
            for (int k = 0; k < 2; ++k) {
                const int row = 2 * g + k;
                #pragma unroll
                for (int u = 0; u < 25; ++u) wreg[100 + k * 25 + u] = Wxp[row * 200 + colbase + u];
            }
        }
        if (t < 400) {
            const int br = t & 3;
            #pragma unroll
            for (int cc = 0; cc < 38; ++cc) {
                const int gc = 38 * br + cc;
                wreg[150 + cc] = (gc < 150) ? W2[t * 150 + gc] : 0.f;
            }
            sc[0] = b2[t];
            sc[1] = sigf(tau_n2[t]);
        }
        if (t < 200) sc[5] = Wd[(t < 100 ? 0 : 100) + (t % 100)];
        if (t < 100) { sc[2] = sigf(tau_m2[t]); sc[3] = bxp[t]; sc[4] = bm[t]; st[3] = 1.6f; }
        else if (t < 200) sc[4] = ba[t - 100];
        if (t < 2) { sc[6] = sigf(tau_md[t]); sc[7] = bd[t]; }
    } else if (t < 506) {
        const int n = t - 456;
        #pragma unroll
        for (int k = 0; k < 4; ++k) {
            #pragma unroll
            for (int u = 0; u < 32; ++u) {
                const int gc = 32 * k + u;
                wreg[k * 32 + u] = (gc < 126) ? W1[(4 * n + k) * 126 + gc] : 0.f;
            }
            sc[k]     = b1[4 * n + k];
            sc[4 + k] = sigf(tau_n1[4 * n + k]);
        }
        sc[8] = sigf(tau_m1[n]);
    }

    // layer-1 step: kin1P = [xt, s1_prev]; updates d1/m1/s1 in-thread, writes s1stage
    auto l1_step = [&]() {
        float pr0 = sc[0], pr1 = sc[1], pr2 = sc[2], pr3 = sc[3];
        #pragma unroll
        for (int u4 = 0; u4 < 8; ++u4) {
            const float4 a0 = *reinterpret_cast<const float4*>(&kin1P[ 0 + 4 * u4]);
            const float4 a1 = *reinterpret_cast<const float4*>(&kin1P[32 + 4 * u4]);
            const float4 a2 = *reinterpret_cast<const float4*>(&kin1P[64 + 4 * u4]);
            const float4 a3 = *reinterpret_cast<const float4*>(&kin1P[96 + 4 * u4]);
            pr0 = fmaf(wreg[      4*u4+0], a0.x, pr0); pr0 = fmaf(wreg[      4*u4+1], a0.y, pr0);
            pr0 = fmaf(wreg[      4*u4+2], a0.z, pr0); pr0 = fmaf(wreg[      4*u4+3], a0.w, pr0);
            pr1 = fmaf(wreg[ 32 + 4*u4+0], a1.x, pr1); pr1 = fmaf(wreg[ 32 + 4*u4+1], a1.y, pr1);
            pr1 = fmaf(wreg[ 32 + 4*u4+2], a1.z, pr1); pr1 = fmaf(wreg[ 32 + 4*u4+3], a1.w, pr1);
            pr2 = fmaf(wreg[ 64 + 4*u4+0], a2.x, pr2); pr2 = fmaf(wreg[ 64 + 4*u4+1], a2.y, pr2);
            pr2 = fmaf(wreg[ 64 + 4*u4+2], a2.z, pr2); pr2 = fmaf(wreg[ 64 + 4*u4+3], a2.w, pr2);
            pr3 = fmaf(wreg[ 96 + 4*u4+0], a3.x, pr3); pr3 = fmaf(wreg[ 96 + 4*u4+1], a3.y, pr3);
            pr3 = fmaf(wreg[ 96 + 4*u4+2], a3.z, pr3); pr3 = fmaf(wreg[ 96 + 4*u4+3], a3.w, pr3);
        }
        const float d0 = sc[4] * st[0] + (1.f - sc[4]) * pr0;
        const float d1 = sc[5] * st[1] + (1.f - sc[5]) * pr1;
        const float d2 = sc[6] * st[2] + (1.f - sc[6]) * pr2;
        const float d3 = sc[7] * st[3] + (1.f - sc[7]) * pr3;
        st[0] = d0; st[1] = d1; st[2] = d2; st[3] = d3;
        const float sum = ((d0 + d1) + d2) + d3;
        st[4] = sc[8] * st[4] + (1.f - sc[8]) * sum - st[5];
        st[5] = (st[4] - 1.0f > 0.f) ? 1.f : 0.f;
        s1stage[t - 456] = st[5];
    };

    __syncthreads();
    if (t < 100) lbP[PIDX(t)] = 1.6f;   // bth init = b_j0
    if (t < 19) {
        const float4 v = *reinterpret_cast<const float4*>(x + (size_t)blk * SEQ * IND + 4 * t);
        *reinterpret_cast<float4*>(&kin1P[4 * t]) = v;   // xt(0)
    }
    __syncthreads();
    if (t >= 456 && t < 506) l1_step();   // L1 step 0 (s1 part of kin1P is zeros)
    __syncthreads();
    if (t >= 128 && t < 178) {            // s1(0) -> kin buffers
        const int i2 = t - 128;
        const float v = s1stage[i2];
        kin1P[76 + i2] = v;
        const int w = i2 / 38;
        kin2P[w][i2 - 38 * w] = v;
    }
    if (t < 19) {                          // xt(1)
        const float4 v = *reinterpret_cast<const float4*>(x + ((size_t)blk * SEQ + 1) * IND + 4 * t);
        *reinterpret_cast<float4*>(&kin1P[4 * t]) = v;
    }
    __syncthreads();

    for (int j = 0; j < SEQ; ++j) {
        // ================= B0: L2(j) + early tiles + L1(j+1) + prefetch issue =================
        if (t >= 456) {
            if (t < 506 && j < SEQ - 1) l1_step();
        } else {
            if (t < 400) {
                const float* kw = kin2P[t & 3];
                float a0 = 0.f, a1 = 0.f, a2 = 0.f, a3 = 0.f;
                #pragma unroll
                for (int cc = 0; cc < 9; ++cc) {
                    const float4 av = *reinterpret_cast<const float4*>(kw + 4 * cc);
                    a0 = fmaf(wreg[150 + 4*cc + 0], av.x, a0);
                    a1 = fmaf(wreg[150 + 4*cc + 1], av.y, a1);
                    a2 = fmaf(wreg[150 + 4*cc + 2], av.z, a2);
                    a3 = fmaf(wreg[150 + 4*cc + 3], av.w, a3);
                }
                a0 = fmaf(wreg[186], kw[36], a0);
                a1 = fmaf(wreg[187], kw[37], a1);
                const float proj = sc[0] + ((a0 + a1) + (a2 + a3));
                st[0] = sc[1] * st[0] + (1.f - sc[1]) * proj;
                dsum[t] = st[0];
            }
            if (t < 200) {
                const int g = t >> 2, c = t & 3;
                {   // stage2-early over lm (tauM rows) or lb (tauA rows)
                    const float* ap = ((g < 25) ? lmP : lbP) + 28 * c;
                    float e0=0.f, e1=0.f, e2=0.f, e3=0.f;
                    #pragma unroll
                    for (int u4 = 0; u4 < 6; ++u4) {
                        const float4 av = *reinterpret_cast<const float4*>(ap + 4 * u4);
                        e0 = fmaf(wreg[  0 + 4*u4+0], av.x, e0); e0 = fmaf(wreg[  0 + 4*u4+1], av.y, e0);
                        e0 = fmaf(wreg[  0 + 4*u4+2], av.z, e0); e0 = fmaf(wreg[  0 + 4*u4+3], av.w, e0);
                        e1 = fmaf(wreg[ 25 + 4*u4+0], av.x, e1); e1 = fmaf(wreg[ 25 + 4*u4+1], av.y, e1);
                        e1 = fmaf(wreg[ 25 + 4*u4+2], av.z, e1); e1 = fmaf(wreg[ 25 + 4*u4+3], av.w, e1);
                        e2 = fmaf(wreg[ 50 + 4*u4+0], av.x, e2); e2 = fmaf(wreg[ 50 + 4*u4+1], av.y, e2);
                        e2 = fmaf(wreg[ 50 + 4*u4+2], av.z, e2); e2 = fmaf(wreg[ 50 + 4*u4+3], av.w, e2);
                        e3 = fmaf(wreg[ 75 + 4*u4+0], av.x, e3); e3 = fmaf(wreg[ 75 + 4*u4+1], av.y, e3);
                        e3 = fmaf(wreg[ 75 + 4*u4+2], av.z, e3); e3 = fmaf(wreg[ 75 + 4*u4+3], av.w, e3);
                    }
                    const float al = ap[24];
                    e0 = fmaf(wreg[24], al, e0); e1 = fmaf(wreg[49], al, e1);
                    e2 = fmaf(wreg[74], al, e2); e3 = fmaf(wreg[99], al, e3);
                    spart[c][4*g+0] = e0; spart[c][4*g+1] = e1;
                    spart[c][4*g+2] = e2; spart[c][4*g+3] = e3;
                }
                {   // dx-early over ls
                    const float* ap = lsP + 28 * c;
                    float f0 = 0.f, f1 = 0.f;
                    #pragma unroll
                    for (int u4 = 0; u4 < 6; ++u4) {
                        const float4 av = *reinterpret_cast<const float4*>(ap + 4 * u4);
                        f0 = fmaf(wreg[100 + 4*u4+0], av.x, f0); f0 = fmaf(wreg[100 + 4*u4+1], av.y, f0);
                        f0 = fmaf(wreg[100 + 4*u4+2], av.z, f0); f0 = fmaf(wreg[100 + 4*u4+3], av.w, f0);
                        f1 = fmaf(wreg[125 + 4*u4+0], av.x, f1); f1 = fmaf(wreg[125 + 4*u4+1], av.y, f1);
                        f1 = fmaf(wreg[125 + 4*u4+2], av.z, f1); f1 = fmaf(wreg[125 + 4*u4+3], av.w, f1);
                    }
                    const float al = ap[24];
                    f0 = fmaf(wreg[124], al, f0);
                    f1 = fmaf(wreg[149], al, f1);
                    dpart[c][2*g+0] = f0;
                    dpart[c][2*g+1] = f1;
                }
                rpart[t] = sc[5] * lsP[PIDX(t % 100)];   // readout partial for ls(j-1)
            } else if (t < 219) {
                if (j + 2 < SEQ)
                    xp0 = *reinterpret_cast<const float4*>(x + ((size_t)blk * SEQ + (j + 2)) * IND + 4 * (t - 200));
            }
        }
        __syncthreads();
        // ================= B1: m2/s2 update; readout reduce lvl1 =================
        if (t < 100) {
            const float4 dv = *reinterpret_cast<const float4*>(&dsum[4 * t]);
            const float sum = ((dv.x + dv.y) + dv.z) + dv.w;
            st[1] = sc[2] * st[1] + (1.f - sc[2]) * sum - st[7];
            st[7] = (st[1] - 1.0f > 0.f) ? 1.f : 0.f;
            const int col = 50 + t, w = col / 38;
            kin2P[w][col - 38 * w] = st[7];
            s2P[PIDX(t)] = st[7];
        } else if (t >= 256 && t < 264) {
            const int rr = t - 256;
            float sV = 0.f;
            #pragma unroll
            for (int u = 0; u < 25; ++u) sV += rpart[25 * rr + u];
            r2[rr] = sV;
        }
        __syncthreads();
        // ================= B2: dx-late over s2(j); xt prefetch write =================
        if (t >= 256 && t < 456) {
            const int s = t - 256;
            const int g = s >> 2, c = s & 3;
            const float* ap = s2P + 28 * c;
            float f0 = 0.f, f1 = 0.f;
            #pragma unroll
            for (int u4 = 0; u4 < 6; ++u4) {
                const float4 av = *reinterpret_cast<const float4*>(ap + 4 * u4);
                f0 = fmaf(wreg[100 + 4*u4+0], av.x, f0); f0 = fmaf(wreg[100 + 4*u4+1], av.y, f0);
                f0 = fmaf(wreg[100 + 4*u4+2], av.z, f0); f0 = fmaf(wreg[100 + 4*u4+3], av.w, f0);
                f1 = fmaf(wreg[125 + 4*u4+0], av.x, f1); f1 = fmaf(wreg[125 + 4*u4+1], av.y, f1);
                f1 = fmaf(wreg[125 + 4*u4+2], av.z, f1); f1 = fmaf(wreg[125 + 4*u4+3], av.w, f1);
            }
            const float al = ap[24];
            f0 = fmaf(wreg[124], al, f0);
            f1 = fmaf(wreg[149], al, f1);
            dpart[4 + c][2*g+0] = f0;
            dpart[4 + c][2*g+1] = f1;
        } else if (t >= 200 && t < 219) {
            if (j + 2 < SEQ)
                *reinterpret_cast<float4*>(&kin1P[4 * (t - 200)]) = xp0;
        }
        __syncthreads();
        // ================= B3: dx reduce; md(j-1) update =================
        if (t < 100) {
            const float sV = (((dpart[4][t] + dpart[5][t]) + (dpart[6][t] + dpart[7][t]))
                            + ((dpart[0][t] + dpart[1][t]) + (dpart[2][t] + dpart[3][t]))) + sc[3];
            st[5] = sV;
            dxP[PIDX(t)] = sV;
        }
        if (t < 2 && j >= 1) {
            const float dot = ((r2[4*t+0] + r2[4*t+1]) + (r2[4*t+2] + r2[4*t+3])) + sc[7];
            mdr = sc[6] * mdr + (1.f - sc[6]) * dot;
            if (j >= 2) accr += mdr;
        }
        __syncthreads();
        // ================= B4: stage2-late over dx =================
        if (t >= 256 && t < 456) {
            const int s = t - 256;
            const int g = s >> 2, c = s & 3;
            const float* ap = dxP + 28 * c;
            float e0=0.f, e1=0.f, e2=0.f, e3=0.f;
            #pragma unroll
            for (int u4 = 0; u4 < 6; ++u4) {
                const float4 av = *reinterpret_cast<const float4*>(ap + 4 * u4);
                e0 = fmaf(wreg[  0 + 4*u4+0], av.x, e0); e0 = fmaf(wreg[  0 + 4*u4+1], av.y, e0);
                e0 = fmaf(wreg[  0 + 4*u4+2], av.z, e0); e0 = fmaf(wreg[  0 + 4*u4+3], av.w, e0);
                e1 = fmaf(wreg[ 25 + 4*u4+0], av.x, e1); e1 = fmaf(wreg[ 25 + 4*u4+1], av.y, e1);
                e1 = fmaf(wreg[ 25 + 4*u4+2], av.z, e1); e1 = fmaf(wreg[ 25 + 4*u4+3], av.w, e1);
                e2 = fmaf(wreg[ 50 + 4*u4+0], av.x, e2); e2 = fmaf(wreg[ 50 + 4*u4+1], av.y, e2);
                e2 = fmaf(wreg[ 50 + 4*u4+2], av.z, e2); e2 = fmaf(wreg[ 50 + 4*u4+3], av.w, e2);
                e3 = fmaf(wreg[ 75 + 4*u4+0], av.x, e3); e3 = fmaf(wreg[ 75 + 4*u4+1], av.y, e3);
                e3 = fmaf(wreg[ 75 + 4*u4+2], av.z, e3); e3 = fmaf(wreg[ 75 + 4*u4+3], av.w, e3);
            }
            const float al = ap[24];
            e0 = fmaf(wreg[24], al, e0); e1 = fmaf(wreg[49], al, e1);
            e2 = fmaf(wreg[74], al, e2); e3 = fmaf(wreg[99], al, e3);
            spart[4 + c][4*g+0] = e0; spart[4 + c][4*g+1] = e1;
            spart[4 + c][4*g+2] = e2; spart[4 + c][4*g+3] = e3;
        }
        __syncthreads();
        // ================= B5: stage2 reduce + sigmoid =================
        if (t < 200) {
            const float sV = (((spart[4][t] + spart[5][t]) + (spart[6][t] + spart[7][t]))
                            + ((spart[0][t] + spart[1][t]) + (spart[2][t] + spart[3][t]))) + sc[4];
            const float tv = 1.f / (1.f + expf(-sV));
            if (t < 100) st[6] = tv;       // tauM, kept by liquid owner
            else tauA_s[t - 100] = tv;     // tauA via LDS
        }
        __syncthreads();
        // ================= B6: liquid update; s1 stage copy =================
        if (t < 100) {
            const float ta  = tauA_s[t];
            const float lbN = ta * st[3] + (1.f - ta) * st[4];
            const float Bv  = 1.6f + 1.8f * lbN;
            const float lmN = st[2] * st[6] + (1.f - st[6]) * st[5] - Bv * st[4];
            const float lsN = (lmN - Bv > 0.f) ? 1.f : 0.f;
            st[2] = lmN; st[3] = lbN; st[4] = lsN;
            lmP[PIDX(t)] = lmN; lbP[PIDX(t)] = lbN; lsP[PIDX(t)] = lsN;
        } else if (t >= 128 && t < 178) {
            const int i2 = t - 128;
            const float v = s1stage[i2];
            kin1P[76 + i2] = v;
            const int w = i2 / 38;
            kin2P[w][i2 - 38 * w] = v;
        }
        __syncthreads();
    }

    // ================= epilogue: readout of ls(SEQ-1) =================
    if (t < 200) rpart[t] = sc[5] * lsP[PIDX(t % 100)];
    __syncthreads();
    if (t >= 256 && t < 264) {
        const int rr = t - 256;
        float sV = 0.f;
        #pragma unroll
        for (int u = 0; u < 25; ++u) sV += rpart[25 * rr + u];
        r2[rr] = sV;
    }
    __syncthreads();
    if (t < 2) {
        const float dot = ((r2[4*t+0] + r2[4*t+1]) + (r2[4*t+2] + r2[4*t+3])) + sc[7];
        mdr = sc[6] * mdr + (1.f - sc[6]) * dot;
        accr += mdr;
        out[blk * 2 + t] = accr;
    }
}

extern "C" void kernel_launch(void* const* d_in, const int* in_sizes, int n_in,
                              void* d_out, int out_size, void* d_ws, size_t ws_size,
                              hipStream_t stream) {
    const float* x      = (const float*)d_in[0];
    const float* W1     = (const float*)d_in[1];
    const float* b1     = (const float*)d_in[2];
    const float* tau_m1 = (const float*)d_in[3];
    const float* tau_n1 = (const float*)d_in[4];
    const float* W2     = (const float*)d_in[5];
    const float* b2     = (const float*)d_in[6];
    const float* tau_m2 = (const float*)d_in[7];
    const float* tau_n2 = (const float*)d_in[8];
    const float* Wx     = (const float*)d_in[9];
    const float* bx     = (const float*)d_in[10];
    const float* bm     = (const float*)d_in[12];
    const float* Wm     = (const float*)d_in[11];
    const float* Wa     = (const float*)d_in[13];
    const float* ba     = (const float*)d_in[14];
    const float* Wd     = (const float*)d_in[15];
    const float* bd     = (const float*)d_in[16];
    const float* tau_md = (const float*)d_in[17];
    float* out = (float*)d_out;

    const int batch = in_sizes[0] / (SEQ * IND);   // 256
    dhsnn_fwd<<<batch, 512, 0, stream>>>(x, W1, b1, tau_m1, tau_n1,
                                         W2, b2, tau_m2, tau_n2,
                                         Wx, bx, Wm, bm, Wa, ba,
                                         Wd, bd, tau_md, out);
}